// Round 1
// baseline (1528.155 us; speedup 1.0000x reference)
//
#include <hip/hip_runtime.h>
#include <hip/hip_bf16.h>

#define Bn 4
#define Sn 2048
#define Dn 1024
#define Hn 16
#define DHn 64
#define BSn (Bn*Sn)

typedef __attribute__((ext_vector_type(8))) short short8;
typedef __attribute__((ext_vector_type(4))) float float4v;

#if defined(__has_builtin) && __has_builtin(__builtin_amdgcn_exp2f)
#define EXP2(x) __builtin_amdgcn_exp2f(x)
#else
#define EXP2(x) exp2f(x)
#endif

static __device__ __forceinline__ unsigned short f2bf(float f) {
  union { float f; unsigned u; } x; x.f = f;
  unsigned r = x.u + 0x7fffu + ((x.u >> 16) & 1u);
  return (unsigned short)(r >> 16);
}

// ---------------------------------------------------------------------------
// Transpose + fp32->bf16 convert the 4 weight matrices: W[k][n] -> Wt[n][k]
// grid = 4 * 16 * 16 blocks of 256
// ---------------------------------------------------------------------------
__global__ __launch_bounds__(256) void k_transpose_w(
    const float* __restrict__ Wq, const float* __restrict__ Wk,
    const float* __restrict__ Wv, const float* __restrict__ Wo,
    unsigned short* __restrict__ wt) {
  __shared__ unsigned short lds[64 * 64];
  int bid = blockIdx.x;
  int w = bid >> 8;
  int tk = (bid >> 4) & 15;
  int tn = bid & 15;
  const float* W = (w == 0) ? Wq : (w == 1) ? Wk : (w == 2) ? Wv : Wo;
  int t = threadIdx.x;
  int kl = t >> 2;            // local k row 0..63
  int n0 = (t & 3) * 16;      // local n start
  const float* src = W + (size_t)(tk * 64 + kl) * Dn + tn * 64 + n0;
  float4v f[4];
#pragma unroll
  for (int i = 0; i < 4; ++i) f[i] = ((const float4v*)src)[i];
#pragma unroll
  for (int c = 0; c < 2; ++c) {
    short8 v;
#pragma unroll
    for (int i = 0; i < 8; ++i) {
      int e = c * 8 + i;
      v[i] = (short)f2bf(f[e >> 2][e & 3]);
    }
    int cc = ((n0 >> 3) + c) ^ (kl & 7);
    *(short8*)(&lds[kl * 64 + cc * 8]) = v;
  }
  __syncthreads();
  int nl = t >> 2;            // local n row 0..63
  int k0 = (t & 3) * 16;
  short8 o0, o1;
#pragma unroll
  for (int j = 0; j < 16; ++j) {
    int kk = k0 + j;
    unsigned short val = lds[kk * 64 + (((nl >> 3) ^ (kk & 7)) * 8) + (nl & 7)];
    if (j < 8) o0[j] = (short)val; else o1[j - 8] = (short)val;
  }
  unsigned short* dst = wt + (size_t)w * Dn * Dn + (size_t)(tn * 64 + nl) * Dn + tk * 64 + k0;
  *(short8*)dst = o0;
  *(short8*)(dst + 8) = o1;
}

// ---------------------------------------------------------------------------
// Transpose V[B,H,S,DH] bf16 -> Vt[B,H,DH,S] bf16.  grid = B*H*32
// ---------------------------------------------------------------------------
__global__ __launch_bounds__(256) void k_transpose_v(
    const unsigned short* __restrict__ V, unsigned short* __restrict__ Vt) {
  __shared__ unsigned short lds[64 * 64];
  int bid = blockIdx.x;
  int bh = bid >> 5;
  int ts = bid & 31;
  int t = threadIdx.x;
  int sl = t >> 2;            // local s 0..63
  int d0 = (t & 3) * 16;
  const unsigned short* src = V + ((size_t)bh * Sn + ts * 64 + sl) * DHn + d0;
  short8 a = *(const short8*)src;
  short8 b = *(const short8*)(src + 8);
  int c0 = d0 >> 3;
  *(short8*)(&lds[sl * 64 + ((c0) ^ (sl & 7)) * 8]) = a;
  *(short8*)(&lds[sl * 64 + ((c0 + 1) ^ (sl & 7)) * 8]) = b;
  __syncthreads();
  int dl = t >> 2;            // local d 0..63
  int s0 = (t & 3) * 16;
  short8 o0, o1;
#pragma unroll
  for (int j = 0; j < 16; ++j) {
    int ss = s0 + j;
    unsigned short val = lds[ss * 64 + (((dl >> 3) ^ (ss & 7)) * 8) + (dl & 7)];
    if (j < 8) o0[j] = (short)val; else o1[j - 8] = (short)val;
  }
  unsigned short* dst = Vt + ((size_t)bh * DHn + dl) * Sn + ts * 64 + s0;
  *(short8*)dst = o0;
  *(short8*)(dst + 8) = o1;
}

// ---------------------------------------------------------------------------
// GEMM: C[M=8192, N=1024] = A[M,K=1024] @ W + bias, via Wt[n][k] bf16.
// MODE 0: A fp32 (converted in staging), output bf16 scattered to [B,H,S,DH]
// MODE 1: A bf16, output fp32 [M,N] (d_out)
// Block 128x128, BK=64, 4 waves (2x2), 16x16x32 bf16 MFMA.
// grid = dim3(8, 64)
// ---------------------------------------------------------------------------
template <int MODE>
__global__ __launch_bounds__(256) void k_gemm(
    const void* __restrict__ Aptr, const unsigned short* __restrict__ Bt,
    const float* __restrict__ bias, void* __restrict__ Cptr) {
  __shared__ unsigned short lA[128 * 64];
  __shared__ unsigned short lB[128 * 64];
  int t = threadIdx.x;
  int bm = blockIdx.y, bn = blockIdx.x;
  int wid = t >> 6, lane = t & 63;
  int l15 = lane & 15, quad = lane >> 4;
  int wm = (wid >> 1) * 64, wn = (wid & 1) * 64;
  float4v acc[4][4] = {};
  int arow = t >> 1;          // 0..127
  int acol = (t & 1) * 32;    // 0 or 32
  for (int kt = 0; kt < 16; ++kt) {
    __syncthreads();
    if (MODE == 0) {
      const float* A = (const float*)Aptr + (size_t)(bm * 128 + arow) * Dn + kt * 64 + acol;
#pragma unroll
      for (int c = 0; c < 4; ++c) {
        float4v g0 = ((const float4v*)A)[c * 2];
        float4v g1 = ((const float4v*)A)[c * 2 + 1];
        short8 v;
#pragma unroll
        for (int i = 0; i < 4; ++i) { v[i] = (short)f2bf(g0[i]); v[i + 4] = (short)f2bf(g1[i]); }
        int cc = ((acol >> 3) + c) ^ (arow & 7);
        *(short8*)(&lA[arow * 64 + cc * 8]) = v;
      }
    } else {
      const unsigned short* A = (const unsigned short*)Aptr + (size_t)(bm * 128 + arow) * Dn + kt * 64 + acol;
#pragma unroll
      for (int c = 0; c < 4; ++c) {
        short8 v = ((const short8*)A)[c];
        int cc = ((acol >> 3) + c) ^ (arow & 7);
        *(short8*)(&lA[arow * 64 + cc * 8]) = v;
      }
    }
    {
      const unsigned short* Bp = Bt + (size_t)(bn * 128 + arow) * Dn + kt * 64 + acol;
#pragma unroll
      for (int c = 0; c < 4; ++c) {
        short8 v = ((const short8*)Bp)[c];
        int cc = ((acol >> 3) + c) ^ (arow & 7);
        *(short8*)(&lB[arow * 64 + cc * 8]) = v;
      }
    }
    __syncthreads();
#pragma unroll
    for (int ks = 0; ks < 2; ++ks) {
      short8 af[4], bfr[4];
#pragma unroll
      for (int mt = 0; mt < 4; ++mt) {
        int row = wm + mt * 16 + l15;
        int cc = (ks * 4 + quad) ^ (row & 7);
        af[mt] = *(const short8*)(&lA[row * 64 + cc * 8]);
      }
#pragma unroll
      for (int nt = 0; nt < 4; ++nt) {
        int row = wn + nt * 16 + l15;
        int cc = (ks * 4 + quad) ^ (row & 7);
        bfr[nt] = *(const short8*)(&lB[row * 64 + cc * 8]);
      }
#pragma unroll
      for (int mt = 0; mt < 4; ++mt)
#pragma unroll
        for (int nt = 0; nt < 4; ++nt)
          acc[mt][nt] = __builtin_amdgcn_mfma_f32_16x16x32_bf16(af[mt], bfr[nt], acc[mt][nt], 0, 0, 0);
    }
  }
#pragma unroll
  for (int nt = 0; nt < 4; ++nt) {
    int gc = bn * 128 + wn + nt * 16 + l15;
    float bv = bias[gc];
#pragma unroll
    for (int mt = 0; mt < 4; ++mt) {
#pragma unroll
      for (int r = 0; r < 4; ++r) {
        int gr = bm * 128 + wm + mt * 16 + quad * 4 + r;
        float val = acc[mt][nt][r] + bv;
        if (MODE == 0) {
          int bb = gr >> 11, s = gr & (Sn - 1);
          int h = gc >> 6, dh = gc & 63;
          ((unsigned short*)Cptr)[(((size_t)bb * Hn + h) * Sn + s) * DHn + dh] = f2bf(val);
        } else {
          ((float*)Cptr)[(size_t)gr * Dn + gc] = val;
        }
      }
    }
  }
}

// ---------------------------------------------------------------------------
// Fused attention: per workgroup = (b*H+h, 64 Q-rows).
// Pass A: QK^T via MFMA, online (m,l) only. Pass B: recompute scores, write
// alpha (fp32, normalized), P C-layout->A-layout via per-wave LDS, PV MFMA.
// grid = B*H*32 = 2048 blocks of 256 (4 waves, 16 Q-rows each)
// Round-0 changes vs 1660us baseline:
//   T1  XCD head-cluster swizzle: bid=(obid&7)*256+(obid>>3) -> 8 heads/XCD,
//       K+Vt working set/L2 = 8*512KB = 4MB (fits). K/V re-reads -> L2 hits.
//   T5  s_setprio(1) around all three MFMA clusters (attn-shaped, m191 +4-7%)
//   T13 defer-max: skip l-rescale when __all(mx <= m_run+8) (m239 pattern)
//   hoisted m*L2E out of pass-B kt loop; fmaf-folded scale*log2e
// ---------------------------------------------------------------------------
__global__ __launch_bounds__(256) void k_attn(
    const unsigned short* __restrict__ Q, const unsigned short* __restrict__ K,
    const unsigned short* __restrict__ Vt, float* __restrict__ alpha_out,
    unsigned short* __restrict__ attn_out) {
  __shared__ unsigned short lK[64 * 64];
  __shared__ unsigned short lV[64 * 64];        // Vt tile: row=d, col=k
  __shared__ unsigned short lP[4 * 16 * 64];    // per-wave alpha tile
  int t = threadIdx.x;
  // T1: bijective XCD swizzle (2048 % 8 == 0). XCD x gets heads [8x, 8x+8).
  int obid = blockIdx.x;
  int bid = (obid & 7) * 256 + (obid >> 3);
  int bh = bid >> 5;
  int qb = bid & 31;
  int wid = t >> 6, lane = t & 63;
  int l15 = lane & 15, quad = lane >> 4;
  const float scale = 0.125f;
  const float L2E = 1.44269504089f;
  const float CSL = 0.125f * 1.44269504089f;   // scale * log2(e)

  short8 qf[2];
  {
    const unsigned short* qp = Q + ((size_t)bh * Sn + qb * 64 + wid * 16 + l15) * DHn + quad * 8;
    qf[0] = *(const short8*)qp;
    qf[1] = *(const short8*)(qp + 32);
  }
  float m_run[4], l_run[4];
#pragma unroll
  for (int r = 0; r < 4; ++r) { m_run[r] = -1e30f; l_run[r] = 0.f; }

  const unsigned short* Kbase = K + (size_t)bh * Sn * DHn;
  const unsigned short* Vtbase = Vt + (size_t)bh * DHn * Sn;
  int srow = t >> 3;   // 0..31
  int sc = t & 7;

  // -------- pass A --------
  for (int kt = 0; kt < 32; ++kt) {
    __syncthreads();
#pragma unroll
    for (int i = 0; i < 2; ++i) {
      int row = srow + i * 32;
      short8 v = *(const short8*)(Kbase + (size_t)(kt * 64 + row) * DHn + sc * 8);
      *(short8*)(&lK[row * 64 + (sc ^ (row & 7)) * 8]) = v;
    }
    __syncthreads();
    float4v sacc[4] = {};
    __builtin_amdgcn_s_setprio(1);
#pragma unroll
    for (int ks = 0; ks < 2; ++ks)
#pragma unroll
      for (int nt = 0; nt < 4; ++nt) {
        int row = nt * 16 + l15;
        int cc = (ks * 4 + quad) ^ (row & 7);
        short8 kfrag = *(const short8*)(&lK[row * 64 + cc * 8]);
        sacc[nt] = __builtin_amdgcn_mfma_f32_16x16x32_bf16(qf[ks], kfrag, sacc[nt], 0, 0, 0);
      }
    __builtin_amdgcn_s_setprio(0);
#pragma unroll
    for (int r = 0; r < 4; ++r) {
      float mx = sacc[0][r];
#pragma unroll
      for (int nt = 1; nt < 4; ++nt) mx = fmaxf(mx, sacc[nt][r]);
      mx *= scale;
      // T13 defer-max: only rescale when some lane's max grew past threshold.
      if (!__all(mx <= m_run[r] + 8.0f)) {
        float mn = fmaxf(m_run[r], mx);
        l_run[r] *= EXP2((m_run[r] - mn) * L2E);
        m_run[r] = mn;
      }
      float l = l_run[r];
      float mb = m_run[r] * L2E;
#pragma unroll
      for (int nt = 0; nt < 4; ++nt)
        l += EXP2(fmaf(sacc[nt][r], CSL, -mb));
      l_run[r] = l;
    }
  }
  // reduce (m,l) across the 16 lanes of each quad group
#pragma unroll
  for (int r = 0; r < 4; ++r) {
    float m = m_run[r], l = l_run[r];
#pragma unroll
    for (int off = 1; off < 16; off <<= 1) {
      float om = __shfl_xor(m, off, 64);
      float ol = __shfl_xor(l, off, 64);
      float mn = fmaxf(m, om);
      l = l * EXP2((m - mn) * L2E) + ol * EXP2((om - mn) * L2E);
      m = mn;
    }
    m_run[r] = m;
    l_run[r] = 1.0f / l;
  }
  float mb[4];
#pragma unroll
  for (int r = 0; r < 4; ++r) mb[r] = m_run[r] * L2E;

  // -------- pass B --------
  float4v oacc[4] = {};
  float* arow_base = alpha_out + ((size_t)bh * Sn + qb * 64 + wid * 16) * Sn;
  unsigned short* lPw = &lP[wid * 16 * 64];
  for (int kt = 0; kt < 32; ++kt) {
    __syncthreads();
#pragma unroll
    for (int i = 0; i < 2; ++i) {
      int row = srow + i * 32;
      short8 v = *(const short8*)(Kbase + (size_t)(kt * 64 + row) * DHn + sc * 8);
      *(short8*)(&lK[row * 64 + (sc ^ (row & 7)) * 8]) = v;
      short8 vv = *(const short8*)(Vtbase + (size_t)row * Sn + kt * 64 + sc * 8);
      *(short8*)(&lV[row * 64 + (sc ^ (row & 7)) * 8]) = vv;
    }
    __syncthreads();
    float4v sacc[4] = {};
    __builtin_amdgcn_s_setprio(1);
#pragma unroll
    for (int ks = 0; ks < 2; ++ks)
#pragma unroll
      for (int nt = 0; nt < 4; ++nt) {
        int row = nt * 16 + l15;
        int cc = (ks * 4 + quad) ^ (row & 7);
        short8 kfrag = *(const short8*)(&lK[row * 64 + cc * 8]);
        sacc[nt] = __builtin_amdgcn_mfma_f32_16x16x32_bf16(qf[ks], kfrag, sacc[nt], 0, 0, 0);
      }
    __builtin_amdgcn_s_setprio(0);
#pragma unroll
    for (int nt = 0; nt < 4; ++nt) {
#pragma unroll
      for (int r = 0; r < 4; ++r) {
        float a = EXP2(fmaf(sacc[nt][r], CSL, -mb[r])) * l_run[r];
        int row = quad * 4 + r;
        int col = nt * 16 + l15;
        arow_base[(size_t)row * Sn + kt * 64 + col] = a;
        lPw[row * 64 + (((col >> 3) ^ (row & 7)) * 8) + (col & 7)] = f2bf(a);
      }
    }
    __syncthreads();
    __builtin_amdgcn_s_setprio(1);
#pragma unroll
    for (int ks = 0; ks < 2; ++ks) {
      int ch = ks * 4 + quad;
      short8 pf = *(const short8*)(&lPw[l15 * 64 + (ch ^ (l15 & 7)) * 8]);
#pragma unroll
      for (int nt = 0; nt < 4; ++nt) {
        int row = nt * 16 + l15;
        int cc = ch ^ (row & 7);
        short8 vfrag = *(const short8*)(&lV[row * 64 + cc * 8]);
        oacc[nt] = __builtin_amdgcn_mfma_f32_16x16x32_bf16(pf, vfrag, oacc[nt], 0, 0, 0);
      }
    }
    __builtin_amdgcn_s_setprio(0);
  }
  // store attnout [B,S,H*DH] bf16
  int b = bh >> 4;
  int h = bh & 15;
#pragma unroll
  for (int nt = 0; nt < 4; ++nt)
#pragma unroll
    for (int r = 0; r < 4; ++r) {
      int s = qb * 64 + wid * 16 + quad * 4 + r;
      int dcol = nt * 16 + l15;
      attn_out[((size_t)b * Sn + s) * Dn + h * DHn + dcol] = f2bf(oacc[nt][r]);
    }
}

// ---------------------------------------------------------------------------
extern "C" void kernel_launch(void* const* d_in, const int* in_sizes, int n_in,
                              void* d_out, int out_size, void* d_ws, size_t ws_size,
                              hipStream_t stream) {
  const float* q  = (const float*)d_in[0];
  const float* k  = (const float*)d_in[1];
  const float* v  = (const float*)d_in[2];
  const float* Wq = (const float*)d_in[3];
  const float* bq = (const float*)d_in[4];
  const float* Wk = (const float*)d_in[5];
  const float* bk = (const float*)d_in[6];
  const float* Wv = (const float*)d_in[7];
  const float* bv = (const float*)d_in[8];
  const float* Wo = (const float*)d_in[9];
  const float* bo = (const float*)d_in[10];

  char* ws = (char*)d_ws;
  unsigned short* wt  = (unsigned short*)(ws);                 // 8 MiB: 4 x WtT
  unsigned short* Qb  = (unsigned short*)(ws + (8u  << 20));   // 16 MiB
  unsigned short* Kb  = (unsigned short*)(ws + (24u << 20));   // 16 MiB
  unsigned short* Vb  = (unsigned short*)(ws + (40u << 20));   // 16 MiB (reused for attnout)
  unsigned short* Vtb = (unsigned short*)(ws + (56u << 20));   // 16 MiB -> total 72 MiB
  unsigned short* AOb = Vb;  // V dead after transpose; reuse for attn output

  float* outp = (float*)d_out;
  float* alphap = outp + (size_t)BSn * Dn;

  hipLaunchKernelGGL(k_transpose_w, dim3(1024), dim3(256), 0, stream, Wq, Wk, Wv, Wo, wt);
  dim3 gg(8, 64);
  hipLaunchKernelGGL((k_gemm<0>), gg, dim3(256), 0, stream,
                     (const void*)q, wt + (size_t)0 * Dn * Dn, bq, (void*)Qb);
  hipLaunchKernelGGL((k_gemm<0>), gg, dim3(256), 0, stream,
                     (const void*)k, wt + (size_t)1 * Dn * Dn, bk, (void*)Kb);
  hipLaunchKernelGGL((k_gemm<0>), gg, dim3(256), 0, stream,
                     (const void*)v, wt + (size_t)2 * Dn * Dn, bv, (void*)Vb);
  hipLaunchKernelGGL(k_transpose_v, dim3(2048), dim3(256), 0, stream, Vb, Vtb);
  hipLaunchKernelGGL(k_attn, dim3(2048), dim3(256), 0, stream, Qb, Kb, Vtb, alphap, AOb);
  hipLaunchKernelGGL((k_gemm<1>), gg, dim3(256), 0, stream,
                     (const void*)AOb, wt + (size_t)3 * Dn * Dn, bo, (void*)d_out);
}